// Round 1
// baseline (739.756 us; speedup 1.0000x reference)
//
#include <hip/hip_runtime.h>
#include <cstdint>
#include <cstddef>

#define NN 50000
#define NE 200000
#define IND 768
#define HID 256
#define OUTD 64

typedef __bf16 bf16;
typedef __bf16 bf16x8 __attribute__((ext_vector_type(8)));
typedef float f32x4 __attribute__((ext_vector_type(4)));

__device__ __forceinline__ void atomAddF(float* p, float v) {
  __hip_atomic_fetch_add(p, v, __ATOMIC_RELAXED, __HIP_MEMORY_SCOPE_AGENT);
}

// ---------------- stage 0: last-edge scatter (last write wins) ----------------
__global__ __launch_bounds__(256) void k_scatter_last(const int* __restrict__ ei,
                                                      int* __restrict__ le) {
  int e = blockIdx.x * 256 + threadIdx.x;
  if (e < NE) atomicMax(&le[ei[e]], e);  // src = ei[0..E)
}

__global__ __launch_bounds__(256) void k_xmod(const float* __restrict__ x,
                                              const int* __restrict__ le,
                                              const int* __restrict__ etype,
                                              const float* __restrict__ eemb,
                                              bf16* __restrict__ xmod) {
  int row = blockIdx.y;
  int col = blockIdx.x * 256 + threadIdx.x;  // IND = 3*256
  int l = le[row];
  float v = x[(size_t)row * IND + col];
  if (l >= 0) v += eemb[etype[l] * IND + col];
  xmod[(size_t)row * IND + col] = (bf16)v;
}

// W [K, NC] fp32 -> Wt [NC, K] bf16
__global__ __launch_bounds__(256) void k_transpose(const float* __restrict__ W,
                                                   bf16* __restrict__ Wt, int K, int NC) {
  int k = blockIdx.x * 256 + threadIdx.x;
  int n = blockIdx.y;
  if (k < K) Wt[n * K + k] = (bf16)W[k * NC + n];
}

// ---------------- MFMA GEMM: C[M,NC] = A[M,K] * Bt[NC,K]^T ----------------
// 128x128 tile, BK=32, 4 waves in 2x2, each wave 64x64 (4x4 of 16x16x32 MFMA)
template <typename OutT>
__global__ __launch_bounds__(256) void k_gemm_bt(const bf16* __restrict__ A,
                                                 const bf16* __restrict__ Bt,
                                                 OutT* __restrict__ C,
                                                 int M, int K, int NC) {
  __shared__ bf16 As[128 * 32];
  __shared__ bf16 Bs[128 * 32];
  const int tid = threadIdx.x;
  const int lane = tid & 63;
  const int wave = tid >> 6;
  const int wr = wave >> 1, wc = wave & 1;
  const int ln15 = lane & 15, q = lane >> 4;
  const int m0 = blockIdx.x * 128;
  const int n0 = blockIdx.y * 128;
  const int r0 = tid >> 2;          // 0..63 (staging row)
  const int ce = (tid & 3) << 3;    // staging col elem: 0,8,16,24

  f32x4 acc[4][4] = {};

  for (int kt = 0; kt < K; kt += 32) {
    // global -> regs (rows clamped: padded rows compute garbage, never stored)
    int ra1 = min(m0 + r0, M - 1) * K + kt + ce;
    int ra2 = min(m0 + 64 + r0, M - 1) * K + kt + ce;
    int rb1 = min(n0 + r0, NC - 1) * K + kt + ce;
    int rb2 = min(n0 + 64 + r0, NC - 1) * K + kt + ce;
    int4 va1 = *(const int4*)(A + ra1);
    int4 va2 = *(const int4*)(A + ra2);
    int4 vb1 = *(const int4*)(Bt + rb1);
    int4 vb2 = *(const int4*)(Bt + rb2);
    __syncthreads();  // prev iter's ds_reads done
    *(int4*)(As + r0 * 32 + ce) = va1;
    *(int4*)(As + (64 + r0) * 32 + ce) = va2;
    *(int4*)(Bs + r0 * 32 + ce) = vb1;
    *(int4*)(Bs + (64 + r0) * 32 + ce) = vb2;
    __syncthreads();
    bf16x8 af[4], bf[4];
#pragma unroll
    for (int i = 0; i < 4; i++)
      af[i] = *(const bf16x8*)(As + (wr * 64 + i * 16 + ln15) * 32 + q * 8);
#pragma unroll
    for (int i = 0; i < 4; i++)
      bf[i] = *(const bf16x8*)(Bs + (wc * 64 + i * 16 + ln15) * 32 + q * 8);
#pragma unroll
    for (int mi = 0; mi < 4; mi++)
#pragma unroll
      for (int ni = 0; ni < 4; ni++)
        acc[mi][ni] = __builtin_amdgcn_mfma_f32_16x16x32_bf16(af[mi], bf[ni], acc[mi][ni], 0, 0, 0);
  }
  // epilogue: C/D layout col=lane&15, row=(lane>>4)*4+reg
#pragma unroll
  for (int mi = 0; mi < 4; mi++)
#pragma unroll
    for (int ni = 0; ni < 4; ni++)
#pragma unroll
      for (int r = 0; r < 4; r++) {
        int row = m0 + wr * 64 + mi * 16 + q * 4 + r;
        int col = n0 + wc * 64 + ni * 16 + ln15;
        if (row < M && col < NC) C[(size_t)row * NC + col] = (OutT)acc[mi][ni][r];
      }
}

// ---------------- attention logits: al[n,h] = sum_d h1[n,h*64+d]*a[h*64+d] ----------------
__global__ __launch_bounds__(256) void k_al1(const bf16* __restrict__ h1,
                                             const float* __restrict__ aS,
                                             const float* __restrict__ aD,
                                             float* __restrict__ alS, float* __restrict__ alD) {
  int n = blockIdx.x, f = threadIdx.x;
  float hv = (float)h1[(size_t)n * HID + f];
  float s1 = hv * aS[f], s2 = hv * aD[f];
#pragma unroll
  for (int off = 32; off; off >>= 1) { s1 += __shfl_xor(s1, off); s2 += __shfl_xor(s2, off); }
  if ((f & 63) == 0) { alS[n * 4 + (f >> 6)] = s1; alD[n * 4 + (f >> 6)] = s2; }
}

// ---------------- edge pass 1: denom + weighted aggregation (shift-free softmax) ----------------
__global__ __launch_bounds__(256) void k_edge1(const int* __restrict__ ei,
                                               const bf16* __restrict__ h1,
                                               const float* __restrict__ alS,
                                               const float* __restrict__ alD,
                                               float* __restrict__ d1, float* __restrict__ agg1) {
  int e = blockIdx.x;
  int f = threadIdx.x;
  int s = ei[e], d = ei[NE + e];
  int hd = f >> 6;
  float logit = alS[s * 4 + hd] + alD[d * 4 + hd];
  logit = logit >= 0.f ? logit : 0.2f * logit;  // LeakyReLU
  float w = __expf(logit);                      // bounded: |logit| small by construction
  if ((f & 63) == 0) atomAddF(&d1[d * 4 + hd], w);
  float v = (float)h1[(size_t)s * HID + f] * w;
  atomAddF(&agg1[(size_t)d * HID + f], v);
}

// ---------------- LN + ELU (fused, with denom normalization) ----------------
__global__ __launch_bounds__(256) void k_ln1(const float* __restrict__ agg1,
                                             const float* __restrict__ d1,
                                             const float* __restrict__ b1,
                                             const float* __restrict__ g1,
                                             const float* __restrict__ be1,
                                             bf16* __restrict__ hln) {
  __shared__ float red[8];
  int n = blockIdx.x, f = threadIdx.x;
  float den = d1[n * 4 + (f >> 6)];
  float v = den > 0.f ? agg1[(size_t)n * HID + f] / den : 0.f;
  v += b1[f];
  float s = v, ss = v * v;
#pragma unroll
  for (int off = 32; off; off >>= 1) { s += __shfl_xor(s, off); ss += __shfl_xor(ss, off); }
  if ((f & 63) == 0) { red[f >> 6] = s; red[4 + (f >> 6)] = ss; }
  __syncthreads();
  float tot = red[0] + red[1] + red[2] + red[3];
  float tss = red[4] + red[5] + red[6] + red[7];
  float mu = tot * (1.f / HID);
  float var = tss * (1.f / HID) - mu * mu;
  float y = (v - mu) * rsqrtf(var + 1e-5f) * g1[f] + be1[f];
  y = y > 0.f ? y : __expf(y) - 1.f;  // ELU
  hln[(size_t)n * HID + f] = (bf16)y;
}

// ---------------- layer-2 logits (head=1, 64 dims; 4 nodes/block) ----------------
__global__ __launch_bounds__(256) void k_al2(const float* __restrict__ h2,
                                             const float* __restrict__ aS,
                                             const float* __restrict__ aD,
                                             float* __restrict__ alS, float* __restrict__ alD) {
  int n = blockIdx.x * 4 + (threadIdx.x >> 6);
  int f = threadIdx.x & 63;
  float hv = h2[(size_t)n * OUTD + f];
  float s1 = hv * aS[f], s2 = hv * aD[f];
#pragma unroll
  for (int off = 32; off; off >>= 1) { s1 += __shfl_xor(s1, off); s2 += __shfl_xor(s2, off); }
  if (f == 0) { alS[n] = s1; alD[n] = s2; }
}

__global__ __launch_bounds__(256) void k_edge2(const int* __restrict__ ei,
                                               const float* __restrict__ h2,
                                               const float* __restrict__ alS,
                                               const float* __restrict__ alD,
                                               float* __restrict__ d2, float* __restrict__ agg2) {
  int e = blockIdx.x * 4 + (threadIdx.x >> 6);
  int f = threadIdx.x & 63;
  int s = ei[e], d = ei[NE + e];
  float logit = alS[s] + alD[d];
  logit = logit >= 0.f ? logit : 0.2f * logit;
  float w = __expf(logit);
  if (f == 0) atomAddF(&d2[d], w);
  atomAddF(&agg2[(size_t)d * OUTD + f], h2[(size_t)s * OUTD + f] * w);
}

__global__ __launch_bounds__(256) void k_ln2(const float* __restrict__ agg2,
                                             const float* __restrict__ d2,
                                             const float* __restrict__ b2,
                                             const float* __restrict__ g2,
                                             const float* __restrict__ be2,
                                             float* __restrict__ out) {
  int n = blockIdx.x * 4 + (threadIdx.x >> 6);
  int f = threadIdx.x & 63;
  float den = d2[n];
  float v = den > 0.f ? agg2[(size_t)n * OUTD + f] / den : 0.f;
  v += b2[f];
  float s = v, ss = v * v;
#pragma unroll
  for (int off = 32; off; off >>= 1) { s += __shfl_xor(s, off); ss += __shfl_xor(ss, off); }
  float mu = s * (1.f / OUTD);
  float var = ss * (1.f / OUTD) - mu * mu;
  out[(size_t)n * OUTD + f] = (v - mu) * rsqrtf(var + 1e-5f) * g2[f] + be2[f];
}

extern "C" void kernel_launch(void* const* d_in, const int* in_sizes, int n_in,
                              void* d_out, int out_size, void* d_ws, size_t ws_size,
                              hipStream_t stream) {
  const float* x    = (const float*)d_in[0];
  const int*   ei   = (const int*)d_in[1];
  const int*   et   = (const int*)d_in[2];
  const float* eemb = (const float*)d_in[3];
  const float* W1   = (const float*)d_in[4];
  const float* as1  = (const float*)d_in[5];
  const float* ad1  = (const float*)d_in[6];
  const float* b1   = (const float*)d_in[7];
  const float* g1   = (const float*)d_in[8];
  const float* be1  = (const float*)d_in[9];
  const float* W2   = (const float*)d_in[10];
  const float* as2  = (const float*)d_in[11];
  const float* ad2  = (const float*)d_in[12];
  const float* b2   = (const float*)d_in[13];
  const float* g2   = (const float*)d_in[14];
  const float* be2  = (const float*)d_in[15];
  float* out = (float*)d_out;

  char* base = (char*)d_ws;
  size_t off = 0;
  auto alloc = [&](size_t bytes) -> void* {
    void* p = base + off;
    off = (off + bytes + 255) & ~(size_t)255;
    return p;
  };
  int*   le   = (int*)alloc((size_t)NN * 4);
  bf16*  h1   = (bf16*)alloc((size_t)NN * HID * 2);
  float* alS1 = (float*)alloc((size_t)NN * 4 * 4);
  float* alD1 = (float*)alloc((size_t)NN * 4 * 4);
  float* d1   = (float*)alloc((size_t)NN * 4 * 4);
  bf16*  hln  = (bf16*)alloc((size_t)NN * HID * 2);
  float* h2   = (float*)alloc((size_t)NN * OUTD * 4);
  float* alS2 = (float*)alloc((size_t)NN * 4);
  float* alD2 = (float*)alloc((size_t)NN * 4);
  float* d2   = (float*)alloc((size_t)NN * 4);
  float* agg2 = (float*)alloc((size_t)NN * OUTD * 4);
  bf16*  W1t  = (bf16*)alloc((size_t)HID * IND * 2);
  bf16*  W2t  = (bf16*)alloc((size_t)OUTD * HID * 2);
  // union region: xmod (bf16, 76.8MB) lives until GEMM1; agg1 (fp32, 51.2MB) after
  void* uni = alloc((size_t)NN * IND * 2);
  bf16*  xmod = (bf16*)uni;
  float* agg1 = (float*)uni;

  hipMemsetAsync(le, 0xFF, (size_t)NN * 4, stream);             // -1
  hipMemsetAsync(d1, 0, (size_t)NN * 16, stream);
  hipMemsetAsync(d2, 0, (size_t)NN * 4, stream);
  hipMemsetAsync(agg2, 0, (size_t)NN * OUTD * 4, stream);

  k_scatter_last<<<(NE + 255) / 256, 256, 0, stream>>>(ei, le);
  k_transpose<<<dim3(3, HID), 256, 0, stream>>>(W1, W1t, IND, HID);
  k_transpose<<<dim3(1, OUTD), 256, 0, stream>>>(W2, W2t, HID, OUTD);
  k_xmod<<<dim3(3, NN), 256, 0, stream>>>(x, le, et, eemb, xmod);

  k_gemm_bt<bf16><<<dim3((NN + 127) / 128, 2), 256, 0, stream>>>(xmod, W1t, h1, NN, IND, HID);
  hipMemsetAsync(agg1, 0, (size_t)NN * HID * 4, stream);        // xmod dead now

  k_al1<<<NN, 256, 0, stream>>>(h1, as1, ad1, alS1, alD1);
  k_edge1<<<NE, 256, 0, stream>>>(ei, h1, alS1, alD1, d1, agg1);
  k_ln1<<<NN, 256, 0, stream>>>(agg1, d1, b1, g1, be1, hln);

  k_gemm_bt<float><<<dim3((NN + 127) / 128, 1), 256, 0, stream>>>(hln, W2t, h2, NN, HID, OUTD);

  k_al2<<<NN / 4, 256, 0, stream>>>(h2, as2, ad2, alS2, alD2);
  k_edge2<<<NE / 4, 256, 0, stream>>>(ei, h2, alS2, alD2, d2, agg2);
  k_ln2<<<NN / 4, 256, 0, stream>>>(agg2, d2, b2, g2, be2, out);
}

// Round 2
// 534.175 us; speedup vs baseline: 1.3849x; 1.3849x over previous
//
#include <hip/hip_runtime.h>
#include <cstdint>
#include <cstddef>

#define NN 50000
#define NE 200000
#define IND 768
#define HID 256
#define OUTD 64
#define NB 196  // ceil(NN/256)

typedef __bf16 bf16;
typedef __bf16 bf16x8 __attribute__((ext_vector_type(8)));
typedef float f32x4 __attribute__((ext_vector_type(4)));

// ---------------- stage 0: last-edge scatter (last write wins) ----------------
__global__ __launch_bounds__(256) void k_scatter_last(const int* __restrict__ ei,
                                                      int* __restrict__ le) {
  int e = blockIdx.x * 256 + threadIdx.x;
  if (e < NE) atomicMax(&le[ei[e]], e);
}

__global__ __launch_bounds__(256) void k_xmod(const float* __restrict__ x,
                                              const int* __restrict__ le,
                                              const int* __restrict__ etype,
                                              const float* __restrict__ eemb,
                                              bf16* __restrict__ xmod) {
  int row = blockIdx.y;
  int col = blockIdx.x * 256 + threadIdx.x;
  int l = le[row];
  float v = x[(size_t)row * IND + col];
  if (l >= 0) v += eemb[etype[l] * IND + col];
  xmod[(size_t)row * IND + col] = (bf16)v;
}

// ---------------- CSR build: histogram -> scan -> scatter ----------------
__global__ __launch_bounds__(256) void k_hist(const int* __restrict__ ei, int* __restrict__ deg) {
  int e = blockIdx.x * 256 + threadIdx.x;
  if (e < NE) atomicAdd(&deg[ei[NE + e]], 1);
}

__global__ __launch_bounds__(256) void k_scan_block(const int* __restrict__ deg,
                                                    int* __restrict__ excl, int* __restrict__ bsum) {
  __shared__ int sm[256];
  int tid = threadIdx.x;
  int i = blockIdx.x * 256 + tid;
  int v = (i < NN) ? deg[i] : 0;
  sm[tid] = v;
  __syncthreads();
#pragma unroll
  for (int off = 1; off < 256; off <<= 1) {
    int t = (tid >= off) ? sm[tid - off] : 0;
    __syncthreads();
    sm[tid] += t;
    __syncthreads();
  }
  if (i < NN) excl[i] = sm[tid] - v;
  if (tid == 255) bsum[blockIdx.x] = sm[255];
}

__global__ __launch_bounds__(256) void k_scan_partials(const int* __restrict__ bsum,
                                                       int* __restrict__ bbase) {
  __shared__ int sm[256];
  int tid = threadIdx.x;
  int v = (tid < NB) ? bsum[tid] : 0;
  sm[tid] = v;
  __syncthreads();
#pragma unroll
  for (int off = 1; off < 256; off <<= 1) {
    int t = (tid >= off) ? sm[tid - off] : 0;
    __syncthreads();
    sm[tid] += t;
    __syncthreads();
  }
  bbase[tid] = sm[tid] - v;
}

__global__ __launch_bounds__(256) void k_add_base(const int* __restrict__ excl,
                                                  const int* __restrict__ bbase,
                                                  int* __restrict__ rowstart, int* __restrict__ cur) {
  int i = blockIdx.x * 256 + threadIdx.x;
  if (i < NN) {
    int rs = excl[i] + bbase[i >> 8];
    rowstart[i] = rs;
    cur[i] = rs;
  }
}

__global__ __launch_bounds__(256) void k_scatter_csr(const int* __restrict__ ei,
                                                     int* __restrict__ cur, int* __restrict__ csr) {
  int e = blockIdx.x * 256 + threadIdx.x;
  if (e < NE) {
    int d = ei[NE + e];
    int pos = atomicAdd(&cur[d], 1);
    csr[pos] = ei[e];  // store src node id
  }
}

// W [K, NC] fp32 -> Wt [NC, K] bf16
__global__ __launch_bounds__(256) void k_transpose(const float* __restrict__ W,
                                                   bf16* __restrict__ Wt, int K, int NC) {
  int k = blockIdx.x * 256 + threadIdx.x;
  int n = blockIdx.y;
  if (k < K) Wt[n * K + k] = (bf16)W[k * NC + n];
}

// ---------------- MFMA GEMM: C[M,NC] = A[M,K] * Bt[NC,K]^T ----------------
template <typename OutT>
__global__ __launch_bounds__(256) void k_gemm_bt(const bf16* __restrict__ A,
                                                 const bf16* __restrict__ Bt,
                                                 OutT* __restrict__ C,
                                                 int M, int K, int NC) {
  __shared__ bf16 As[128 * 32];
  __shared__ bf16 Bs[128 * 32];
  const int tid = threadIdx.x;
  const int lane = tid & 63;
  const int wave = tid >> 6;
  const int wr = wave >> 1, wc = wave & 1;
  const int ln15 = lane & 15, q = lane >> 4;
  const int m0 = blockIdx.x * 128;
  const int n0 = blockIdx.y * 128;
  const int r0 = tid >> 2;
  const int ce = (tid & 3) << 3;

  f32x4 acc[4][4] = {};

  for (int kt = 0; kt < K; kt += 32) {
    int ra1 = min(m0 + r0, M - 1) * K + kt + ce;
    int ra2 = min(m0 + 64 + r0, M - 1) * K + kt + ce;
    int rb1 = min(n0 + r0, NC - 1) * K + kt + ce;
    int rb2 = min(n0 + 64 + r0, NC - 1) * K + kt + ce;
    int4 va1 = *(const int4*)(A + ra1);
    int4 va2 = *(const int4*)(A + ra2);
    int4 vb1 = *(const int4*)(Bt + rb1);
    int4 vb2 = *(const int4*)(Bt + rb2);
    __syncthreads();
    *(int4*)(As + r0 * 32 + ce) = va1;
    *(int4*)(As + (64 + r0) * 32 + ce) = va2;
    *(int4*)(Bs + r0 * 32 + ce) = vb1;
    *(int4*)(Bs + (64 + r0) * 32 + ce) = vb2;
    __syncthreads();
    bf16x8 af[4], bfr[4];
#pragma unroll
    for (int i = 0; i < 4; i++)
      af[i] = *(const bf16x8*)(As + (wr * 64 + i * 16 + ln15) * 32 + q * 8);
#pragma unroll
    for (int i = 0; i < 4; i++)
      bfr[i] = *(const bf16x8*)(Bs + (wc * 64 + i * 16 + ln15) * 32 + q * 8);
#pragma unroll
    for (int mi = 0; mi < 4; mi++)
#pragma unroll
      for (int ni = 0; ni < 4; ni++)
        acc[mi][ni] = __builtin_amdgcn_mfma_f32_16x16x32_bf16(af[mi], bfr[ni], acc[mi][ni], 0, 0, 0);
  }
#pragma unroll
  for (int mi = 0; mi < 4; mi++)
#pragma unroll
    for (int ni = 0; ni < 4; ni++)
#pragma unroll
      for (int r = 0; r < 4; r++) {
        int row = m0 + wr * 64 + mi * 16 + q * 4 + r;
        int col = n0 + wc * 64 + ni * 16 + ln15;
        if (row < M && col < NC) C[(size_t)row * NC + col] = (OutT)acc[mi][ni][r];
      }
}

// ---------------- attention logits layer 1 ----------------
__global__ __launch_bounds__(256) void k_al1(const bf16* __restrict__ h1,
                                             const float* __restrict__ aS,
                                             const float* __restrict__ aD,
                                             float* __restrict__ alS, float* __restrict__ alD) {
  int n = blockIdx.x, f = threadIdx.x;
  float hv = (float)h1[(size_t)n * HID + f];
  float s1 = hv * aS[f], s2 = hv * aD[f];
#pragma unroll
  for (int off = 32; off; off >>= 1) { s1 += __shfl_xor(s1, off); s2 += __shfl_xor(s2, off); }
  if ((f & 63) == 0) { alS[n * 4 + (f >> 6)] = s1; alD[n * 4 + (f >> 6)] = s2; }
}

// ---------------- fused gather-aggregate + LN + ELU, layer 1 ----------------
__global__ __launch_bounds__(256) void k_agg_ln1(const int* __restrict__ rowstart,
                                                 const int* __restrict__ deg,
                                                 const int* __restrict__ csr,
                                                 const bf16* __restrict__ h1,
                                                 const float* __restrict__ alS,
                                                 const float* __restrict__ alD,
                                                 const float* __restrict__ b1,
                                                 const float* __restrict__ g1,
                                                 const float* __restrict__ be1,
                                                 bf16* __restrict__ hln) {
  __shared__ float red[8];
  int n = blockIdx.x, f = threadIdx.x, hd = f >> 6;
  int start = rowstart[n], cnt = deg[n];
  float ald = alD[n * 4 + hd];
  float accv = 0.f, accw = 0.f;
  for (int j = 0; j < cnt; j++) {
    int s = csr[start + j];
    float logit = alS[s * 4 + hd] + ald;
    logit = logit >= 0.f ? logit : 0.2f * logit;
    float w = __expf(logit);  // shift-free softmax: logits bounded by construction
    accv += w * (float)h1[(size_t)s * HID + f];
    accw += w;
  }
  float v = (cnt > 0) ? accv / accw : 0.f;
  v += b1[f];
  float s = v, ss = v * v;
#pragma unroll
  for (int off = 32; off; off >>= 1) { s += __shfl_xor(s, off); ss += __shfl_xor(ss, off); }
  if ((f & 63) == 0) { red[f >> 6] = s; red[4 + (f >> 6)] = ss; }
  __syncthreads();
  float tot = red[0] + red[1] + red[2] + red[3];
  float tss = red[4] + red[5] + red[6] + red[7];
  float mu = tot * (1.f / HID);
  float var = tss * (1.f / HID) - mu * mu;
  float y = (v - mu) * rsqrtf(var + 1e-5f) * g1[f] + be1[f];
  y = y > 0.f ? y : __expf(y) - 1.f;  // ELU
  hln[(size_t)n * HID + f] = (bf16)y;
}

// ---------------- layer-2 logits ----------------
__global__ __launch_bounds__(256) void k_al2(const float* __restrict__ h2,
                                             const float* __restrict__ aS,
                                             const float* __restrict__ aD,
                                             float* __restrict__ alS, float* __restrict__ alD) {
  int n = blockIdx.x * 4 + (threadIdx.x >> 6);
  int f = threadIdx.x & 63;
  float hv = h2[(size_t)n * OUTD + f];
  float s1 = hv * aS[f], s2 = hv * aD[f];
#pragma unroll
  for (int off = 32; off; off >>= 1) { s1 += __shfl_xor(s1, off); s2 += __shfl_xor(s2, off); }
  if (f == 0) { alS[n] = s1; alD[n] = s2; }
}

// ---------------- fused gather-aggregate + LN, layer 2 ----------------
__global__ __launch_bounds__(64) void k_agg_ln2(const int* __restrict__ rowstart,
                                                const int* __restrict__ deg,
                                                const int* __restrict__ csr,
                                                const float* __restrict__ h2,
                                                const float* __restrict__ alS,
                                                const float* __restrict__ alD,
                                                const float* __restrict__ b2,
                                                const float* __restrict__ g2,
                                                const float* __restrict__ be2,
                                                float* __restrict__ out) {
  int n = blockIdx.x, f = threadIdx.x;
  int start = rowstart[n], cnt = deg[n];
  float ald = alD[n];
  float accv = 0.f, accw = 0.f;
  for (int j = 0; j < cnt; j++) {
    int s = csr[start + j];
    float logit = alS[s] + ald;
    logit = logit >= 0.f ? logit : 0.2f * logit;
    float w = __expf(logit);
    accv += w * h2[(size_t)s * OUTD + f];
    accw += w;
  }
  float v = (cnt > 0) ? accv / accw : 0.f;
  v += b2[f];
  float s = v, ss = v * v;
#pragma unroll
  for (int off = 32; off; off >>= 1) { s += __shfl_xor(s, off); ss += __shfl_xor(ss, off); }
  float mu = s * (1.f / OUTD);
  float var = ss * (1.f / OUTD) - mu * mu;
  out[(size_t)n * OUTD + f] = (v - mu) * rsqrtf(var + 1e-5f) * g2[f] + be2[f];
}

extern "C" void kernel_launch(void* const* d_in, const int* in_sizes, int n_in,
                              void* d_out, int out_size, void* d_ws, size_t ws_size,
                              hipStream_t stream) {
  const float* x    = (const float*)d_in[0];
  const int*   ei   = (const int*)d_in[1];
  const int*   et   = (const int*)d_in[2];
  const float* eemb = (const float*)d_in[3];
  const float* W1   = (const float*)d_in[4];
  const float* as1  = (const float*)d_in[5];
  const float* ad1  = (const float*)d_in[6];
  const float* b1   = (const float*)d_in[7];
  const float* g1   = (const float*)d_in[8];
  const float* be1  = (const float*)d_in[9];
  const float* W2   = (const float*)d_in[10];
  const float* as2  = (const float*)d_in[11];
  const float* ad2  = (const float*)d_in[12];
  const float* b2   = (const float*)d_in[13];
  const float* g2   = (const float*)d_in[14];
  const float* be2  = (const float*)d_in[15];
  float* out = (float*)d_out;

  char* base = (char*)d_ws;
  size_t off = 0;
  auto alloc = [&](size_t bytes) -> void* {
    void* p = base + off;
    off = (off + bytes + 255) & ~(size_t)255;
    return p;
  };
  int*   le    = (int*)alloc((size_t)NN * 4);
  int*   deg   = (int*)alloc((size_t)NN * 4);
  int*   excl  = (int*)alloc((size_t)NN * 4);
  int*   bsum  = (int*)alloc(256 * 4);
  int*   bbase = (int*)alloc(256 * 4);
  int*   rowst = (int*)alloc((size_t)NN * 4);
  int*   cur   = (int*)alloc((size_t)NN * 4);
  int*   csr   = (int*)alloc((size_t)NE * 4);
  bf16*  h1    = (bf16*)alloc((size_t)NN * HID * 2);
  float* alS1  = (float*)alloc((size_t)NN * 4 * 4);
  float* alD1  = (float*)alloc((size_t)NN * 4 * 4);
  bf16*  hln   = (bf16*)alloc((size_t)NN * HID * 2);
  float* h2    = (float*)alloc((size_t)NN * OUTD * 4);
  float* alS2  = (float*)alloc((size_t)NN * 4);
  float* alD2  = (float*)alloc((size_t)NN * 4);
  bf16*  W1t   = (bf16*)alloc((size_t)HID * IND * 2);
  bf16*  W2t   = (bf16*)alloc((size_t)OUTD * HID * 2);
  bf16*  xmod  = (bf16*)alloc((size_t)NN * IND * 2);

  hipMemsetAsync(le, 0xFF, (size_t)NN * 4, stream);   // -1
  hipMemsetAsync(deg, 0, (size_t)NN * 4, stream);

  // CSR build + last-edge scatter
  k_scatter_last<<<(NE + 255) / 256, 256, 0, stream>>>(ei, le);
  k_hist<<<(NE + 255) / 256, 256, 0, stream>>>(ei, deg);
  k_scan_block<<<NB, 256, 0, stream>>>(deg, excl, bsum);
  k_scan_partials<<<1, 256, 0, stream>>>(bsum, bbase);
  k_add_base<<<NB, 256, 0, stream>>>(excl, bbase, rowst, cur);
  k_scatter_csr<<<(NE + 255) / 256, 256, 0, stream>>>(ei, cur, csr);

  // weights + x_mod
  k_transpose<<<dim3(3, HID), 256, 0, stream>>>(W1, W1t, IND, HID);
  k_transpose<<<dim3(1, OUTD), 256, 0, stream>>>(W2, W2t, HID, OUTD);
  k_xmod<<<dim3(3, NN), 256, 0, stream>>>(x, le, et, eemb, xmod);

  // layer 1
  k_gemm_bt<bf16><<<dim3((NN + 127) / 128, 2), 256, 0, stream>>>(xmod, W1t, h1, NN, IND, HID);
  k_al1<<<NN, 256, 0, stream>>>(h1, as1, ad1, alS1, alD1);
  k_agg_ln1<<<NN, 256, 0, stream>>>(rowst, deg, csr, h1, alS1, alD1, b1, g1, be1, hln);

  // layer 2
  k_gemm_bt<float><<<dim3((NN + 127) / 128, 1), 256, 0, stream>>>(hln, W2t, h2, NN, HID, OUTD);
  k_al2<<<NN / 4, 256, 0, stream>>>(h2, as2, ad2, alS2, alD2);
  k_agg_ln2<<<NN, 64, 0, stream>>>(rowst, deg, csr, h2, alS2, alD2, b2, g2, be2, out);
}

// Round 3
// 479.993 us; speedup vs baseline: 1.5412x; 1.1129x over previous
//
#include <hip/hip_runtime.h>
#include <cstdint>
#include <cstddef>

#define NN 50000
#define NE 200000
#define IND 768
#define HID 256
#define OUTD 64
#define NB 196  // ceil(NN/256)

typedef __bf16 bf16;
typedef __bf16 bf16x8 __attribute__((ext_vector_type(8)));
typedef float f32x4 __attribute__((ext_vector_type(4)));

// ---------------- edge prep: last-write-wins scatter index + dst histogram ----------------
__global__ __launch_bounds__(256) void k_edge_prep(const int* __restrict__ ei,
                                                   int* __restrict__ le, int* __restrict__ deg) {
  int e = blockIdx.x * 256 + threadIdx.x;
  if (e < NE) {
    atomicMax(&le[ei[e]], e);        // src: last edge index wins
    atomicAdd(&deg[ei[NE + e]], 1);  // dst degree
  }
}

// ---------------- CSR build: scan + scatter ----------------
__global__ __launch_bounds__(256) void k_scan_block(const int* __restrict__ deg,
                                                    int* __restrict__ excl, int* __restrict__ bsum) {
  __shared__ int sm[256];
  int tid = threadIdx.x;
  int i = blockIdx.x * 256 + tid;
  int v = (i < NN) ? deg[i] : 0;
  sm[tid] = v;
  __syncthreads();
#pragma unroll
  for (int off = 1; off < 256; off <<= 1) {
    int t = (tid >= off) ? sm[tid - off] : 0;
    __syncthreads();
    sm[tid] += t;
    __syncthreads();
  }
  if (i < NN) excl[i] = sm[tid] - v;
  if (tid == 255) bsum[blockIdx.x] = sm[255];
}

__global__ __launch_bounds__(256) void k_scan_partials(const int* __restrict__ bsum,
                                                       int* __restrict__ bbase) {
  __shared__ int sm[256];
  int tid = threadIdx.x;
  int v = (tid < NB) ? bsum[tid] : 0;
  sm[tid] = v;
  __syncthreads();
#pragma unroll
  for (int off = 1; off < 256; off <<= 1) {
    int t = (tid >= off) ? sm[tid - off] : 0;
    __syncthreads();
    sm[tid] += t;
    __syncthreads();
  }
  bbase[tid] = sm[tid] - v;
}

__global__ __launch_bounds__(256) void k_add_base(const int* __restrict__ excl,
                                                  const int* __restrict__ bbase,
                                                  int* __restrict__ rowstart, int* __restrict__ cur) {
  int i = blockIdx.x * 256 + threadIdx.x;
  if (i < NN) {
    int rs = excl[i] + bbase[i >> 8];
    rowstart[i] = rs;
    cur[i] = rs;
  }
}

__global__ __launch_bounds__(256) void k_scatter_csr(const int* __restrict__ ei,
                                                     int* __restrict__ cur, int* __restrict__ csr) {
  int e = blockIdx.x * 256 + threadIdx.x;
  if (e < NE) {
    int d = ei[NE + e];
    int pos = atomicAdd(&cur[d], 1);
    csr[pos] = ei[e];  // store src node id
  }
}

// W [K, NC] fp32 -> Wt [NC, K] bf16
__global__ __launch_bounds__(256) void k_transpose(const float* __restrict__ W,
                                                   bf16* __restrict__ Wt, int K, int NC) {
  int k = blockIdx.x * 256 + threadIdx.x;
  int n = blockIdx.y;
  if (k < K) Wt[n * K + k] = (bf16)W[k * NC + n];
}

// ---------------- MFMA GEMM: C[M,NC] = A[M,K] * Bt[NC,K]^T ----------------
// 128x128 tile, BK=32, 4 waves 2x2, each wave 64x64 (4x4 of 16x16x32 MFMA).
// FUSE: A is built on the fly as bf16(x[row] + eemb[et[le[row]]]) (x fp32).
// Epilogue also emits attention logits alS/alD (per-row dot with aS/aD),
// exploiting that each (row, 64-col head slice) lives wholly in one wave.
template <typename OutT, bool FUSE>
__global__ __launch_bounds__(256) void k_gemm_bt(const bf16* __restrict__ A,
                                                 const float* __restrict__ Ax,
                                                 const int* __restrict__ le,
                                                 const int* __restrict__ et,
                                                 const float* __restrict__ eemb,
                                                 const bf16* __restrict__ Bt,
                                                 OutT* __restrict__ C,
                                                 int M, int K, int NC,
                                                 const float* __restrict__ aS,
                                                 const float* __restrict__ aD,
                                                 float* __restrict__ alS,
                                                 float* __restrict__ alD,
                                                 int alStride) {
  __shared__ bf16 As[128 * 32];
  __shared__ bf16 Bs[128 * 32];
  const int tid = threadIdx.x;
  const int lane = tid & 63;
  const int wave = tid >> 6;
  const int wr = wave >> 1, wc = wave & 1;
  const int ln15 = lane & 15, q = lane >> 4;
  const int n0 = blockIdx.x * 128;  // n fastest-varying: adjacent blocks share A-tile
  const int m0 = blockIdx.y * 128;
  const int r0 = tid >> 2;
  const int ce = (tid & 3) << 3;

  const int rA1 = min(m0 + r0, M - 1);
  const int rA2 = min(m0 + 64 + r0, M - 1);
  const int rB1 = min(n0 + r0, NC - 1);
  const int rB2 = min(n0 + 64 + r0, NC - 1);

  int e1 = -1, e2 = -1;
  if (FUSE) {
    int l1 = le[rA1]; if (l1 >= 0) e1 = et[l1];
    int l2 = le[rA2]; if (l2 >= 0) e2 = et[l2];
  }

  f32x4 acc[4][4] = {};

  for (int kt = 0; kt < K; kt += 32) {
    bf16x8 va, vb;
    int4 va_i, vb_i;
    if (FUSE) {
      const float* p1 = Ax + (size_t)rA1 * K + kt + ce;
      const float* p2 = Ax + (size_t)rA2 * K + kt + ce;
      float4 a0 = *(const float4*)p1, a1 = *(const float4*)(p1 + 4);
      float4 b0 = *(const float4*)p2, b1 = *(const float4*)(p2 + 4);
      if (e1 >= 0) {
        const float* q1 = eemb + (size_t)e1 * K + kt + ce;
        float4 t0 = *(const float4*)q1, t1 = *(const float4*)(q1 + 4);
        a0.x += t0.x; a0.y += t0.y; a0.z += t0.z; a0.w += t0.w;
        a1.x += t1.x; a1.y += t1.y; a1.z += t1.z; a1.w += t1.w;
      }
      if (e2 >= 0) {
        const float* q2 = eemb + (size_t)e2 * K + kt + ce;
        float4 t0 = *(const float4*)q2, t1 = *(const float4*)(q2 + 4);
        b0.x += t0.x; b0.y += t0.y; b0.z += t0.z; b0.w += t0.w;
        b1.x += t1.x; b1.y += t1.y; b1.z += t1.z; b1.w += t1.w;
      }
      va[0] = (bf16)a0.x; va[1] = (bf16)a0.y; va[2] = (bf16)a0.z; va[3] = (bf16)a0.w;
      va[4] = (bf16)a1.x; va[5] = (bf16)a1.y; va[6] = (bf16)a1.z; va[7] = (bf16)a1.w;
      vb[0] = (bf16)b0.x; vb[1] = (bf16)b0.y; vb[2] = (bf16)b0.z; vb[3] = (bf16)b0.w;
      vb[4] = (bf16)b1.x; vb[5] = (bf16)b1.y; vb[6] = (bf16)b1.z; vb[7] = (bf16)b1.w;
    } else {
      va_i = *(const int4*)(A + (size_t)rA1 * K + kt + ce);
      vb_i = *(const int4*)(A + (size_t)rA2 * K + kt + ce);
    }
    int4 wb1 = *(const int4*)(Bt + (size_t)rB1 * K + kt + ce);
    int4 wb2 = *(const int4*)(Bt + (size_t)rB2 * K + kt + ce);
    __syncthreads();
    if (FUSE) {
      *(bf16x8*)(As + r0 * 32 + ce) = va;
      *(bf16x8*)(As + (64 + r0) * 32 + ce) = vb;
    } else {
      *(int4*)(As + r0 * 32 + ce) = va_i;
      *(int4*)(As + (64 + r0) * 32 + ce) = vb_i;
    }
    *(int4*)(Bs + r0 * 32 + ce) = wb1;
    *(int4*)(Bs + (64 + r0) * 32 + ce) = wb2;
    __syncthreads();
    bf16x8 af[4], bfr[4];
#pragma unroll
    for (int i = 0; i < 4; i++)
      af[i] = *(const bf16x8*)(As + (wr * 64 + i * 16 + ln15) * 32 + q * 8);
#pragma unroll
    for (int i = 0; i < 4; i++)
      bfr[i] = *(const bf16x8*)(Bs + (wc * 64 + i * 16 + ln15) * 32 + q * 8);
#pragma unroll
    for (int mi = 0; mi < 4; mi++)
#pragma unroll
      for (int ni = 0; ni < 4; ni++)
        acc[mi][ni] = __builtin_amdgcn_mfma_f32_16x16x32_bf16(af[mi], bfr[ni], acc[mi][ni], 0, 0, 0);
  }

  // epilogue 1: C store. C/D layout col=lane&15, row=(lane>>4)*4+reg
#pragma unroll
  for (int mi = 0; mi < 4; mi++)
#pragma unroll
    for (int ni = 0; ni < 4; ni++)
#pragma unroll
      for (int r = 0; r < 4; r++) {
        int row = m0 + wr * 64 + mi * 16 + q * 4 + r;
        int col = n0 + wc * 64 + ni * 16 + ln15;
        if (row < M && col < NC) C[(size_t)row * NC + col] = (OutT)acc[mi][ni][r];
      }

  // epilogue 2: attention logits. Each wave's 64-col slice == one head slice
  // (hd constant per wave); each (row, hd) is produced by exactly one wave
  // grid-wide -> plain stores, no atomics.
  if (n0 + wc * 64 < NC) {
    const int hd = (n0 + wc * 64) >> 6;
#pragma unroll
    for (int mi = 0; mi < 4; mi++)
#pragma unroll
      for (int r = 0; r < 4; r++) {
        float ps = 0.f, pd = 0.f;
#pragma unroll
        for (int ni = 0; ni < 4; ni++) {
          int col = n0 + wc * 64 + ni * 16 + ln15;
          float w_s = (col < NC) ? aS[col] : 0.f;
          float w_d = (col < NC) ? aD[col] : 0.f;
          ps += acc[mi][ni][r] * w_s;
          pd += acc[mi][ni][r] * w_d;
        }
#pragma unroll
        for (int off = 1; off < 16; off <<= 1) {
          ps += __shfl_xor(ps, off);
          pd += __shfl_xor(pd, off);
        }
        int row = m0 + wr * 64 + mi * 16 + q * 4 + r;
        if (ln15 == 0 && row < M) {
          alS[row * alStride + hd] = ps;
          alD[row * alStride + hd] = pd;
        }
      }
  }
}

// ---------------- fused gather-aggregate + LN + ELU, layer 1 ----------------
__global__ __launch_bounds__(256) void k_agg_ln1(const int* __restrict__ rowstart,
                                                 const int* __restrict__ deg,
                                                 const int* __restrict__ csr,
                                                 const bf16* __restrict__ h1,
                                                 const float* __restrict__ alS,
                                                 const float* __restrict__ alD,
                                                 const float* __restrict__ b1,
                                                 const float* __restrict__ g1,
                                                 const float* __restrict__ be1,
                                                 bf16* __restrict__ hln) {
  __shared__ float red[8];
  int n = blockIdx.x, f = threadIdx.x, hd = f >> 6;
  int start = rowstart[n], cnt = deg[n];
  float ald = alD[n * 4 + hd];
  float accv = 0.f, accw = 0.f;
  for (int j = 0; j < cnt; j++) {
    int s = csr[start + j];
    float logit = alS[s * 4 + hd] + ald;
    logit = logit >= 0.f ? logit : 0.2f * logit;
    float w = __expf(logit);  // shift-free softmax: logits bounded by construction
    accv += w * (float)h1[(size_t)s * HID + f];
    accw += w;
  }
  float v = (cnt > 0) ? accv / accw : 0.f;
  v += b1[f];
  float s = v, ss = v * v;
#pragma unroll
  for (int off = 32; off; off >>= 1) { s += __shfl_xor(s, off); ss += __shfl_xor(ss, off); }
  if ((f & 63) == 0) { red[f >> 6] = s; red[4 + (f >> 6)] = ss; }
  __syncthreads();
  float tot = red[0] + red[1] + red[2] + red[3];
  float tss = red[4] + red[5] + red[6] + red[7];
  float mu = tot * (1.f / HID);
  float var = tss * (1.f / HID) - mu * mu;
  float y = (v - mu) * rsqrtf(var + 1e-5f) * g1[f] + be1[f];
  y = y > 0.f ? y : __expf(y) - 1.f;  // ELU
  hln[(size_t)n * HID + f] = (bf16)y;
}

// ---------------- fused gather-aggregate + LN, layer 2 ----------------
__global__ __launch_bounds__(64) void k_agg_ln2(const int* __restrict__ rowstart,
                                                const int* __restrict__ deg,
                                                const int* __restrict__ csr,
                                                const float* __restrict__ h2,
                                                const float* __restrict__ alS,
                                                const float* __restrict__ alD,
                                                const float* __restrict__ b2,
                                                const float* __restrict__ g2,
                                                const float* __restrict__ be2,
                                                float* __restrict__ out) {
  int n = blockIdx.x, f = threadIdx.x;
  int start = rowstart[n], cnt = deg[n];
  float ald = alD[n];
  float accv = 0.f, accw = 0.f;
  for (int j = 0; j < cnt; j++) {
    int s = csr[start + j];
    float logit = alS[s] + ald;
    logit = logit >= 0.f ? logit : 0.2f * logit;
    float w = __expf(logit);
    accv += w * h2[(size_t)s * OUTD + f];
    accw += w;
  }
  float v = (cnt > 0) ? accv / accw : 0.f;
  v += b2[f];
  float s = v, ss = v * v;
#pragma unroll
  for (int off = 32; off; off >>= 1) { s += __shfl_xor(s, off); ss += __shfl_xor(ss, off); }
  float mu = s * (1.f / OUTD);
  float var = ss * (1.f / OUTD) - mu * mu;
  out[(size_t)n * OUTD + f] = (v - mu) * rsqrtf(var + 1e-5f) * g2[f] + be2[f];
}

extern "C" void kernel_launch(void* const* d_in, const int* in_sizes, int n_in,
                              void* d_out, int out_size, void* d_ws, size_t ws_size,
                              hipStream_t stream) {
  const float* x    = (const float*)d_in[0];
  const int*   ei   = (const int*)d_in[1];
  const int*   et   = (const int*)d_in[2];
  const float* eemb = (const float*)d_in[3];
  const float* W1   = (const float*)d_in[4];
  const float* as1  = (const float*)d_in[5];
  const float* ad1  = (const float*)d_in[6];
  const float* b1   = (const float*)d_in[7];
  const float* g1   = (const float*)d_in[8];
  const float* be1  = (const float*)d_in[9];
  const float* W2   = (const float*)d_in[10];
  const float* as2  = (const float*)d_in[11];
  const float* ad2  = (const float*)d_in[12];
  const float* b2   = (const float*)d_in[13];
  const float* g2   = (const float*)d_in[14];
  const float* be2  = (const float*)d_in[15];
  float* out = (float*)d_out;

  char* base = (char*)d_ws;
  size_t off = 0;
  auto alloc = [&](size_t bytes) -> void* {
    void* p = base + off;
    off = (off + bytes + 255) & ~(size_t)255;
    return p;
  };
  int*   le    = (int*)alloc((size_t)NN * 4);
  int*   deg   = (int*)alloc((size_t)NN * 4);
  int*   excl  = (int*)alloc((size_t)NN * 4);
  int*   bsum  = (int*)alloc(256 * 4);
  int*   bbase = (int*)alloc(256 * 4);
  int*   rowst = (int*)alloc((size_t)NN * 4);
  int*   cur   = (int*)alloc((size_t)NN * 4);
  int*   csr   = (int*)alloc((size_t)NE * 4);
  bf16*  h1    = (bf16*)alloc((size_t)NN * HID * 2);
  float* alS1  = (float*)alloc((size_t)NN * 4 * 4);
  float* alD1  = (float*)alloc((size_t)NN * 4 * 4);
  bf16*  hln   = (bf16*)alloc((size_t)NN * HID * 2);
  float* h2    = (float*)alloc((size_t)NN * OUTD * 4);
  float* alS2  = (float*)alloc((size_t)NN * 4);
  float* alD2  = (float*)alloc((size_t)NN * 4);
  bf16*  W1t   = (bf16*)alloc((size_t)HID * IND * 2);
  bf16*  W2t   = (bf16*)alloc((size_t)OUTD * HID * 2);

  hipMemsetAsync(le, 0xFF, (size_t)NN * 4, stream);  // -1
  hipMemsetAsync(deg, 0, (size_t)NN * 4, stream);

  // CSR build + last-edge index
  k_edge_prep<<<(NE + 255) / 256, 256, 0, stream>>>(ei, le, deg);
  k_scan_block<<<NB, 256, 0, stream>>>(deg, excl, bsum);
  k_scan_partials<<<1, 256, 0, stream>>>(bsum, bbase);
  k_add_base<<<NB, 256, 0, stream>>>(excl, bbase, rowst, cur);
  k_scatter_csr<<<(NE + 255) / 256, 256, 0, stream>>>(ei, cur, csr);

  // weights
  k_transpose<<<dim3(3, HID), 256, 0, stream>>>(W1, W1t, IND, HID);
  k_transpose<<<dim3(1, OUTD), 256, 0, stream>>>(W2, W2t, HID, OUTD);

  // layer 1: fused (x + edge_emb) -> GEMM -> h1 + logits
  k_gemm_bt<bf16, true><<<dim3(2, (NN + 127) / 128), 256, 0, stream>>>(
      nullptr, x, le, et, eemb, W1t, h1, NN, IND, HID, as1, ad1, alS1, alD1, 4);
  k_agg_ln1<<<NN, 256, 0, stream>>>(rowst, deg, csr, h1, alS1, alD1, b1, g1, be1, hln);

  // layer 2: GEMM -> h2 + logits
  k_gemm_bt<float, false><<<dim3(1, (NN + 127) / 128), 256, 0, stream>>>(
      hln, nullptr, nullptr, nullptr, nullptr, W2t, h2, NN, HID, OUTD, as2, ad2, alS2, alD2, 1);
  k_agg_ln2<<<NN, 64, 0, stream>>>(rowst, deg, csr, h2, alS2, alD2, b2, g2, be2, out);
}